// Round 4
// baseline (327.819 us; speedup 1.0000x reference)
//
#include <hip/hip_runtime.h>
#include <hip/hip_bf16.h>

typedef unsigned short u16;
typedef unsigned int u32;
typedef __attribute__((ext_vector_type(8))) short short8;   // 8 bf16 for MFMA frags
typedef __attribute__((ext_vector_type(8))) u16 ushort8;
typedef __attribute__((ext_vector_type(4))) float f32x4;

// ---------- constants ----------
#define BB 2048
#define SS 8
#define DNUM 8
#define LL 50
#define EDIM 16
#define FDIM 512
#define HID1 256
#define HID2 128
#define KDNN 1216          // 1160 padded to 64-multiple
#define ROWS (BB*LL)       // 102400

// ---------- helpers ----------
__device__ inline u16 f2bf(float x) {
    u32 u = __builtin_bit_cast(u32, x);
    u32 r = (u + 0x7FFFu + ((u >> 16) & 1u)) >> 16;   // RNE
    return (u16)r;
}
__device__ inline float bf2f(u16 b) {
    u32 u = ((u32)b) << 16;
    return __builtin_bit_cast(float, u);
}
__device__ inline void load16_lds(const void* g, void* l) {
    __builtin_amdgcn_global_load_lds(
        (const __attribute__((address_space(1))) u32*)g,
        (__attribute__((address_space(3))) u32*)l, 16, 0, 0);
}
__device__ inline float wave_sum(float v) {
    #pragma unroll
    for (int off = 32; off > 0; off >>= 1) v += __shfl_xor(v, off, 64);
    return v;
}
__device__ inline float wave_max(float v) {
    #pragma unroll
    for (int off = 32; off > 0; off >>= 1) v = fmaxf(v, __shfl_xor(v, off, 64));
    return v;
}
__device__ inline void cvt8(const float4& a, const float4& b, ushort8& o) {
    o[0]=f2bf(a.x); o[1]=f2bf(a.y); o[2]=f2bf(a.z); o[3]=f2bf(a.w);
    o[4]=f2bf(b.x); o[5]=f2bf(b.y); o[6]=f2bf(b.z); o[7]=f2bf(b.w);
}

// ---------- K0: weight prep (combine + transpose + bf16) ----------
__global__ __launch_bounds__(256) void prep_weights(
    const float* __restrict__ w1, const float* __restrict__ dw1,
    const float* __restrict__ dw2,
    u16* __restrict__ WHP_T, u16* __restrict__ WQ_T,
    u16* __restrict__ W1D_T, u16* __restrict__ W2D_T)
{
    int idx = blockIdx.x * 256 + threadIdx.x;
    if (idx < 131072) {
        int n = idx >> 10, k = idx & 1023;
        float v;
        if (k < 512) v = w1[(512 + k) * 128 + n] - w1[(1024 + k) * 128 + n];
        else         v = w1[(1024 + k) * 128 + n];   // 1536 + (k-512)
        WHP_T[n * 1024 + k] = f2bf(v);
    } else if (idx < 196608) {
        int i = idx - 131072;
        int n = i >> 9, k = i & 511;
        WQ_T[n * 512 + k] = f2bf(w1[k * 128 + n] + w1[(1024 + k) * 128 + n]);
    } else if (idx < 507904) {
        int i = idx - 196608;
        int n = i / KDNN, k = i - n * KDNN;
        W1D_T[i] = (k < 1160) ? f2bf(dw1[k * HID1 + n]) : (u16)0;
    } else if (idx < 540672) {
        int i = idx - 507904;
        int n = i >> 8, k = i & 255;
        W2D_T[i] = f2bf(dw2[k * HID2 + n]);
    }
}

// ---------- K1: per-b gather: sparse emb + dense + feed -> dnn_in (bf16), A_q ----------
__global__ __launch_bounds__(256) void gather_b(
    const int* __restrict__ sparse_ids, const float* __restrict__ dense,
    const int* __restrict__ feedid, const float* __restrict__ emb_tables,
    const float* __restrict__ feed_table,
    u16* __restrict__ dnn_in, u16* __restrict__ A_q)
{
    int b = blockIdx.x, t = threadIdx.x;
    u16* drow = dnn_in + (size_t)b * KDNN;
    if (t < 128) {
        int s = t >> 4, e = t & 15;
        int id = sparse_ids[b * SS + s];
        float v = emb_tables[(size_t)s * 1600000 + (size_t)id * EDIM + e];
        drow[t] = f2bf(v);
    } else if (t < 136) {
        drow[t] = f2bf(dense[b * DNUM + (t - 128)]);
    } else if (t < 192) {
        drow[1160 + (t - 136)] = 0;   // K padding
    }
    int fid = feedid[b];
    float2 f = *(const float2*)&feed_table[(size_t)fid * FDIM + t * 2];
    u16 u0 = f2bf(f.x), u1 = f2bf(f.y);
    drow[136 + t * 2] = u0;
    drow[136 + t * 2 + 1] = u1;
    A_q[(size_t)b * FDIM + t * 2] = u0;
    A_q[(size_t)b * FDIM + t * 2 + 1] = u1;
}

// ---------- K2: generic bf16 MFMA GEMM, templated M-tile ----------
template<int BM, bool RELU, bool OUT_BF16>
__global__ __launch_bounds__(256, 4) void gemm_bt(
    const u16* __restrict__ A, int lda,
    const u16* __restrict__ BT, int ldb,
    const float* __restrict__ bias,
    void* __restrict__ Cv, int M, int N, int K)
{
    constexpr int MI = BM / 32;           // frags per wave in M
    __shared__ u16 As[BM * 64];
    __shared__ u16 Bs[128 * 64];
    int m0 = blockIdx.x * BM, n0 = blockIdx.y * 128;
    int tid = threadIdx.x, wave = tid >> 6, lane = tid & 63;
    int lrow = lane >> 3, lk = (lane & 7) * 8;
    f32x4 acc[MI][4];
    f32x4 zz = {0.f, 0.f, 0.f, 0.f};
    #pragma unroll
    for (int i = 0; i < MI; i++)
        #pragma unroll
        for (int j = 0; j < 4; j++) acc[i][j] = zz;
    int wm = (wave >> 1) * (BM / 2), wn = (wave & 1) * 64;

    for (int kt = 0; kt < K; kt += 64) {
        #pragma unroll
        for (int j = 0; j < MI; ++j) {
            int c = wave * MI + j;
            int row = c * 8 + lrow;
            load16_lds(A + (size_t)(m0 + row) * lda + kt + lk, &As[c * 512]);
        }
        #pragma unroll
        for (int j = 0; j < 4; ++j) {
            int c = wave * 4 + j;
            int row = c * 8 + lrow;
            load16_lds(BT + (size_t)(n0 + row) * ldb + kt + lk, &Bs[c * 512]);
        }
        __syncthreads();
        #pragma unroll
        for (int ks = 0; ks < 2; ++ks) {
            int kk = ks * 32 + (lane >> 4) * 8;
            short8 af[MI], bf[4];
            #pragma unroll
            for (int i = 0; i < MI; i++)
                af[i] = *(const short8*)&As[(wm + i * 16 + (lane & 15)) * 64 + kk];
            #pragma unroll
            for (int j = 0; j < 4; j++)
                bf[j] = *(const short8*)&Bs[(wn + j * 16 + (lane & 15)) * 64 + kk];
            #pragma unroll
            for (int i = 0; i < MI; i++)
                #pragma unroll
                for (int j = 0; j < 4; j++)
                    acc[i][j] = __builtin_amdgcn_mfma_f32_16x16x32_bf16(
                        af[i], bf[j], acc[i][j], 0, 0, 0);
        }
        __syncthreads();
    }
    #pragma unroll
    for (int i = 0; i < MI; i++) {
        #pragma unroll
        for (int j = 0; j < 4; j++) {
            #pragma unroll
            for (int r = 0; r < 4; r++) {
                int row = m0 + wm + i * 16 + (lane >> 4) * 4 + r;
                int col = n0 + wn + j * 16 + (lane & 15);
                float v = acc[i][j][r];
                if (bias) v += bias[col];
                if (RELU) v = fmaxf(v, 0.f);
                size_t off = (size_t)row * N + col;
                if (OUT_BF16) ((u16*)Cv)[off] = f2bf(v);
                else ((float*)Cv)[off] = v;
            }
        }
    }
}

// ---------- K3: DIN GEMM, register-resident A, no LDS, no barriers ----------
// Each wave owns 16 rows x K=512. Lane l holds A[row=base+(l&15)]
// [k = f*32 + (l>>4)*8 + 0..7] for f=0..15 — the full h row is gathered in
// one burst at wave start (one fetch per distinct row; L3 serves dups).
// B fragments (WHP_T, 256 KB, L2-resident) read directly from global.
// acc[j]: rows 16, cols j*16+(l&15). Epilogue: score = sum relu(.)*w2 in-wave.
__global__ __launch_bounds__(256, 2) void din_gemm(
    const int* __restrict__ hist_ids, const int* __restrict__ feedid,
    const float* __restrict__ feed_table,
    const u16* __restrict__ WHP_T,
    const float* __restrict__ qw, const float* __restrict__ b1,
    const float* __restrict__ w2v, const float* __restrict__ b2p,
    float* __restrict__ scores)
{
    int t = threadIdx.x, lane = t & 63;
    int rowbase = blockIdx.x * 64 + (t >> 6) * 16;
    int myrow = rowbase + (lane & 15);
    int g = lane >> 4;              // k-group 0..3
    int b = myrow / LL;
    const float* hrow = feed_table + (size_t)hist_ids[myrow] * FDIM + g * 8;
    const float* qrow = feed_table + (size_t)feedid[b] * FDIM + g * 8;

    short8 ah[16], ap[16];
    #pragma unroll
    for (int c = 0; c < 4; ++c) {
        float4 hb[4][2], qb[4][2];
        #pragma unroll
        for (int f = 0; f < 4; ++f) {
            const float* hp = hrow + (c * 4 + f) * 32;
            hb[f][0] = *(const float4*)hp;
            hb[f][1] = *(const float4*)(hp + 4);
        }
        #pragma unroll
        for (int f = 0; f < 4; ++f) {
            const float* qp = qrow + (c * 4 + f) * 32;
            qb[f][0] = *(const float4*)qp;
            qb[f][1] = *(const float4*)(qp + 4);
        }
        #pragma unroll
        for (int f = 0; f < 4; ++f) {
            ushort8 hv, pv;
            cvt8(hb[f][0], hb[f][1], hv);
            float4 p0 = make_float4(hb[f][0].x * qb[f][0].x, hb[f][0].y * qb[f][0].y,
                                    hb[f][0].z * qb[f][0].z, hb[f][0].w * qb[f][0].w);
            float4 p1 = make_float4(hb[f][1].x * qb[f][1].x, hb[f][1].y * qb[f][1].y,
                                    hb[f][1].z * qb[f][1].z, hb[f][1].w * qb[f][1].w);
            cvt8(p0, p1, pv);
            ah[c * 4 + f] = __builtin_bit_cast(short8, hv);
            ap[c * 4 + f] = __builtin_bit_cast(short8, pv);
        }
    }

    f32x4 acc[8];
    f32x4 zz = {0.f, 0.f, 0.f, 0.f};
    #pragma unroll
    for (int j = 0; j < 8; ++j) acc[j] = zz;

    const u16* Bbase = WHP_T + (size_t)(lane & 15) * 1024 + g * 8;
    #pragma unroll
    for (int f = 0; f < 16; ++f) {
        #pragma unroll
        for (int j = 0; j < 8; ++j) {
            const u16* bp_ = Bbase + (size_t)(j * 16) * 1024 + f * 32;
            short8 bh = *(const short8*)bp_;
            short8 bpv = *(const short8*)(bp_ + 512);
            acc[j] = __builtin_amdgcn_mfma_f32_16x16x32_bf16(ah[f], bh, acc[j], 0, 0, 0);
            acc[j] = __builtin_amdgcn_mfma_f32_16x16x32_bf16(ap[f], bpv, acc[j], 0, 0, 0);
        }
    }

    // ---- epilogue: per-row score = sum_col relu(acc + qw + b1) * w2 + b2 ----
    float b2 = b2p[0];
    int colbase = lane & 15;
    #pragma unroll
    for (int r = 0; r < 4; ++r) {
        int gr = rowbase + g * 4 + r;
        int br = gr / LL;
        float s = 0.f;
        #pragma unroll
        for (int j = 0; j < 8; ++j) {
            int col = j * 16 + colbase;
            float v = acc[j][r] + qw[br * 128 + col] + b1[col];
            s += fmaxf(v, 0.f) * w2v[col];
        }
        s += __shfl_xor(s, 1, 64);
        s += __shfl_xor(s, 2, 64);
        s += __shfl_xor(s, 4, 64);
        s += __shfl_xor(s, 8, 64);
        if (colbase == 0) scores[gr] = s + b2;
    }
}

// ---------- K4: softmax over L + user_interest (re-gather h, coalesced) ----------
__global__ __launch_bounds__(256) void softmax_ui(
    const float* __restrict__ scores, const int* __restrict__ hist_ids,
    const float* __restrict__ feed_table, u16* __restrict__ dnn_in)
{
    int b = blockIdx.x, t = threadIdx.x;
    int wave = t >> 6, lane = t & 63;
    __shared__ float sc[56];
    __shared__ int hid[56];
    if (t >= 64 && t < 64 + LL) hid[t - 64] = hist_ids[b * LL + (t - 64)];
    if (wave == 0) {
        float x = (lane < LL) ? scores[b * LL + lane] : -1e30f;
        float mx = wave_max(x);
        float e = (lane < LL) ? __expf(x - mx) : 0.f;
        float s = wave_sum(e);
        if (lane < LL) sc[lane] = e / s;
    }
    __syncthreads();
    int d = t * 2;
    float a0 = 0.f, a1 = 0.f;
    #pragma unroll 5
    for (int l = 0; l < LL; ++l) {
        float2 hv = *(const float2*)&feed_table[(size_t)hid[l] * FDIM + d];
        float al = sc[l];
        a0 += al * hv.x;
        a1 += al * hv.y;
    }
    dnn_in[(size_t)b * KDNN + 648 + d] = f2bf(a0);
    dnn_in[(size_t)b * KDNN + 648 + d + 1] = f2bf(a1);
}

// ---------- K5: MMOE + task heads ----------
__global__ __launch_bounds__(256) void mmoe_head(
    const float* __restrict__ dnn_out, const float* __restrict__ expert_w,
    const float* __restrict__ gate_w, const float* __restrict__ out_w,
    const float* __restrict__ out_b, float* __restrict__ out)
{
    int wave = threadIdx.x >> 6, lane = threadIdx.x & 63;
    int b = blockIdx.x * 4 + wave;
    __shared__ float ds[4][128];
    __shared__ float eo[4][64];
    __shared__ float gt[4][32];
    ds[wave][lane] = dnn_out[b * 128 + lane];
    ds[wave][lane + 64] = dnn_out[b * 128 + 64 + lane];
    __syncthreads();
    int e = lane >> 3, o = lane & 7;
    float acc = 0.f;
    for (int k = 0; k < 128; ++k)
        acc += ds[wave][k] * expert_w[(e * 128 + k) * 8 + o];
    eo[wave][lane] = acc;
    if (lane < 32) {
        int tt = lane >> 3, ee = lane & 7;
        float g = 0.f;
        for (int k = 0; k < 128; ++k)
            g += ds[wave][k] * gate_w[(tt * 128 + k) * 8 + ee];
        float m = g;
        #pragma unroll
        for (int off = 4; off; off >>= 1) m = fmaxf(m, __shfl_xor(m, off, 8));
        float ex = __expf(g - m);
        float s = ex;
        #pragma unroll
        for (int off = 4; off; off >>= 1) s += __shfl_xor(s, off, 8);
        gt[wave][lane] = ex / s;
    }
    __syncthreads();
    if (lane < 32) {
        int tt = lane >> 3, o2 = lane & 7;
        float to = 0.f;
        #pragma unroll
        for (int ee = 0; ee < 8; ++ee)
            to += gt[wave][tt * 8 + ee] * eo[wave][ee * 8 + o2];
        float pl = to * out_w[tt * 8 + o2];
        #pragma unroll
        for (int off = 4; off; off >>= 1) pl += __shfl_xor(pl, off, 8);
        if (o2 == 0) {
            float logit = pl + out_b[tt];
            out[b * 4 + tt] = 1.f / (1.f + __expf(-logit));
        }
    }
}

// ---------- host ----------
extern "C" void kernel_launch(void* const* d_in, const int* in_sizes, int n_in,
                              void* d_out, int out_size, void* d_ws, size_t ws_size,
                              hipStream_t stream)
{
    const int*   sparse_ids = (const int*)d_in[0];
    const float* dense      = (const float*)d_in[1];
    const int*   feedid     = (const int*)d_in[2];
    const int*   hist_ids   = (const int*)d_in[3];
    const float* emb_tables = (const float*)d_in[4];
    const float* feed_table = (const float*)d_in[5];
    const float* attn_w1    = (const float*)d_in[6];
    const float* attn_b1    = (const float*)d_in[7];
    const float* attn_w2    = (const float*)d_in[8];
    const float* attn_b2    = (const float*)d_in[9];
    const float* dnn_w1     = (const float*)d_in[10];
    const float* dnn_b1     = (const float*)d_in[11];
    const float* dnn_w2     = (const float*)d_in[12];
    const float* dnn_b2     = (const float*)d_in[13];
    const float* expert_w   = (const float*)d_in[14];
    const float* gate_w     = (const float*)d_in[15];
    const float* out_w      = (const float*)d_in[16];
    const float* out_b      = (const float*)d_in[17];
    float* out = (float*)d_out;

    char* ws = (char*)d_ws;
    size_t off = 0;
    auto alloc = [&](size_t bytes) {
        char* p = ws + off;
        off += (bytes + 255) & ~(size_t)255;
        return p;
    };
    u16* WHP_T = (u16*)alloc(131072 * 2);
    u16* WQ_T  = (u16*)alloc(65536 * 2);
    u16* W1D_T = (u16*)alloc((size_t)HID1 * KDNN * 2);
    u16* W2D_T = (u16*)alloc((size_t)HID2 * HID1 * 2);
    u16* AQ    = (u16*)alloc((size_t)BB * FDIM * 2);
    float* QW  = (float*)alloc((size_t)BB * 128 * 4);
    u16* DNNIN = (u16*)alloc((size_t)BB * KDNN * 2);
    u16* Z     = (u16*)alloc((size_t)BB * HID1 * 2);
    float* DOUT= (float*)alloc((size_t)BB * HID2 * 4);
    float* SCORES = (float*)alloc((size_t)ROWS * 4);

    prep_weights<<<2112, 256, 0, stream>>>(attn_w1, dnn_w1, dnn_w2,
                                           WHP_T, WQ_T, W1D_T, W2D_T);
    gather_b<<<BB, 256, 0, stream>>>(sparse_ids, dense, feedid, emb_tables,
                                     feed_table, DNNIN, AQ);
    gemm_bt<64, false, false><<<dim3(BB / 64, 1), 256, 0, stream>>>(
        AQ, 512, WQ_T, 512, nullptr, QW, BB, 128, 512);
    din_gemm<<<ROWS / 64, 256, 0, stream>>>(
        hist_ids, feedid, feed_table, WHP_T, QW, attn_b1, attn_w2, attn_b2,
        SCORES);
    softmax_ui<<<BB, 256, 0, stream>>>(SCORES, hist_ids, feed_table, DNNIN);
    gemm_bt<64, true, true><<<dim3(BB / 64, HID1 / 128), 256, 0, stream>>>(
        DNNIN, KDNN, W1D_T, KDNN, dnn_b1, Z, BB, HID1, KDNN);
    gemm_bt<64, true, false><<<dim3(BB / 64, 1), 256, 0, stream>>>(
        Z, HID1, W2D_T, HID1, dnn_b2, DOUT, BB, HID2, HID1);
    mmoe_head<<<BB / 4, 256, 0, stream>>>(DOUT, expert_w, gate_w, out_w,
                                          out_b, out);
}

// Round 5
// 228.855 us; speedup vs baseline: 1.4324x; 1.4324x over previous
//
#include <hip/hip_runtime.h>
#include <hip/hip_bf16.h>

typedef unsigned short u16;
typedef unsigned int u32;
typedef __attribute__((ext_vector_type(8))) short short8;   // 8 bf16 for MFMA frags
typedef __attribute__((ext_vector_type(8))) u16 ushort8;
typedef __attribute__((ext_vector_type(4))) float f32x4;

// ---------- constants ----------
#define BB 2048
#define SS 8
#define DNUM 8
#define LL 50
#define EDIM 16
#define FDIM 512
#define HID1 256
#define HID2 128
#define KDNN 1216          // 1160 padded to 64-multiple
#define ROWS (BB*LL)       // 102400

// ---------- helpers ----------
__device__ inline u16 f2bf(float x) {
    u32 u = __builtin_bit_cast(u32, x);
    u32 r = (u + 0x7FFFu + ((u >> 16) & 1u)) >> 16;   // RNE
    return (u16)r;
}
__device__ inline float bf2f(u16 b) {
    u32 u = ((u32)b) << 16;
    return __builtin_bit_cast(float, u);
}
__device__ inline void load16_lds(const void* g, void* l) {
    __builtin_amdgcn_global_load_lds(
        (const __attribute__((address_space(1))) u32*)g,
        (__attribute__((address_space(3))) u32*)l, 16, 0, 0);
}
__device__ inline float wave_sum(float v) {
    #pragma unroll
    for (int off = 32; off > 0; off >>= 1) v += __shfl_xor(v, off, 64);
    return v;
}
__device__ inline float wave_max(float v) {
    #pragma unroll
    for (int off = 32; off > 0; off >>= 1) v = fmaxf(v, __shfl_xor(v, off, 64));
    return v;
}
__device__ inline void cvt8(const float4& a, const float4& b, ushort8& o) {
    o[0]=f2bf(a.x); o[1]=f2bf(a.y); o[2]=f2bf(a.z); o[3]=f2bf(a.w);
    o[4]=f2bf(b.x); o[5]=f2bf(b.y); o[6]=f2bf(b.z); o[7]=f2bf(b.w);
}

// ---------- K0: weight prep (combine + transpose + bf16) ----------
// WHP_T [128n][1024k]: k<512 -> Wh = W1b-W1c ; k>=512 -> Wp = W1d
// WQ_T  [128n][512k] : Wq = W1a+W1c
// W1D_T [256n][1216k]: dnn_w1^T zero-padded ; W2D_T [128n][256k]: dnn_w2^T
__global__ __launch_bounds__(256) void prep_weights(
    const float* __restrict__ w1, const float* __restrict__ dw1,
    const float* __restrict__ dw2,
    u16* __restrict__ WHP_T, u16* __restrict__ WQ_T,
    u16* __restrict__ W1D_T, u16* __restrict__ W2D_T)
{
    int idx = blockIdx.x * 256 + threadIdx.x;
    if (idx < 131072) {
        int n = idx >> 10, k = idx & 1023;
        float v;
        if (k < 512) v = w1[(512 + k) * 128 + n] - w1[(1024 + k) * 128 + n];
        else         v = w1[(1024 + k) * 128 + n];   // 1536 + (k-512)
        WHP_T[n * 1024 + k] = f2bf(v);
    } else if (idx < 196608) {
        int i = idx - 131072;
        int n = i >> 9, k = i & 511;
        WQ_T[n * 512 + k] = f2bf(w1[k * 128 + n] + w1[(1024 + k) * 128 + n]);
    } else if (idx < 507904) {
        int i = idx - 196608;
        int n = i / KDNN, k = i - n * KDNN;
        W1D_T[i] = (k < 1160) ? f2bf(dw1[k * HID1 + n]) : (u16)0;
    } else if (idx < 540672) {
        int i = idx - 507904;
        int n = i >> 8, k = i & 255;
        W2D_T[i] = f2bf(dw2[k * HID2 + n]);
    }
}

// ---------- K1: per-b gather: sparse emb + dense + feed -> dnn_in (bf16) ----------
__global__ __launch_bounds__(256) void gather_b(
    const int* __restrict__ sparse_ids, const float* __restrict__ dense,
    const int* __restrict__ feedid, const float* __restrict__ emb_tables,
    const float* __restrict__ feed_table,
    u16* __restrict__ dnn_in)
{
    int b = blockIdx.x, t = threadIdx.x;
    u16* drow = dnn_in + (size_t)b * KDNN;
    if (t < 128) {
        int s = t >> 4, e = t & 15;
        int id = sparse_ids[b * SS + s];
        float v = emb_tables[(size_t)s * 1600000 + (size_t)id * EDIM + e];
        drow[t] = f2bf(v);
    } else if (t < 136) {
        drow[t] = f2bf(dense[b * DNUM + (t - 128)]);
    } else if (t < 192) {
        drow[1160 + (t - 136)] = 0;   // K padding
    }
    int fid = feedid[b];
    float2 f = *(const float2*)&feed_table[(size_t)fid * FDIM + t * 2];
    drow[136 + t * 2] = f2bf(f.x);
    drow[136 + t * 2 + 1] = f2bf(f.y);
}

// ---------- K2: generic bf16 MFMA GEMM, templated M-tile (DNN layers) ----------
template<int BM, bool RELU, bool OUT_BF16>
__global__ __launch_bounds__(256, 4) void gemm_bt(
    const u16* __restrict__ A, int lda,
    const u16* __restrict__ BT, int ldb,
    const float* __restrict__ bias,
    void* __restrict__ Cv, int M, int N, int K)
{
    constexpr int MI = BM / 32;           // frags per wave in M
    __shared__ u16 As[BM * 64];
    __shared__ u16 Bs[128 * 64];
    int m0 = blockIdx.x * BM, n0 = blockIdx.y * 128;
    int tid = threadIdx.x, wave = tid >> 6, lane = tid & 63;
    int lrow = lane >> 3, lk = (lane & 7) * 8;
    f32x4 acc[MI][4];
    f32x4 zz = {0.f, 0.f, 0.f, 0.f};
    #pragma unroll
    for (int i = 0; i < MI; i++)
        #pragma unroll
        for (int j = 0; j < 4; j++) acc[i][j] = zz;
    int wm = (wave >> 1) * (BM / 2), wn = (wave & 1) * 64;

    for (int kt = 0; kt < K; kt += 64) {
        #pragma unroll
        for (int j = 0; j < MI; ++j) {
            int c = wave * MI + j;
            int row = c * 8 + lrow;
            load16_lds(A + (size_t)(m0 + row) * lda + kt + lk, &As[c * 512]);
        }
        #pragma unroll
        for (int j = 0; j < 4; ++j) {
            int c = wave * 4 + j;
            int row = c * 8 + lrow;
            load16_lds(BT + (size_t)(n0 + row) * ldb + kt + lk, &Bs[c * 512]);
        }
        __syncthreads();
        #pragma unroll
        for (int ks = 0; ks < 2; ++ks) {
            int kk = ks * 32 + (lane >> 4) * 8;
            short8 af[MI], bf[4];
            #pragma unroll
            for (int i = 0; i < MI; i++)
                af[i] = *(const short8*)&As[(wm + i * 16 + (lane & 15)) * 64 + kk];
            #pragma unroll
            for (int j = 0; j < 4; j++)
                bf[j] = *(const short8*)&Bs[(wn + j * 16 + (lane & 15)) * 64 + kk];
            #pragma unroll
            for (int i = 0; i < MI; i++)
                #pragma unroll
                for (int j = 0; j < 4; j++)
                    acc[i][j] = __builtin_amdgcn_mfma_f32_16x16x32_bf16(
                        af[i], bf[j], acc[i][j], 0, 0, 0);
        }
        __syncthreads();
    }
    #pragma unroll
    for (int i = 0; i < MI; i++) {
        #pragma unroll
        for (int j = 0; j < 4; j++) {
            #pragma unroll
            for (int r = 0; r < 4; r++) {
                int row = m0 + wm + i * 16 + (lane >> 4) * 4 + r;
                int col = n0 + wn + j * 16 + (lane & 15);
                float v = acc[i][j][r];
                if (bias) v += bias[col];
                if (RELU) v = fmaxf(v, 0.f);
                size_t off = (size_t)row * N + col;
                if (OUT_BF16) ((u16*)Cv)[off] = f2bf(v);
                else ((float*)Cv)[off] = v;
            }
        }
    }
}

// ---------- K3: fully-fused DIN: one block per sample b ----------
// W'_b = Wh + diag(q_b).Wp built per K-chunk in LDS (folds q into weights:
// halves MFMA work, no q*h tiles). M=64 (50 rows + pad), K-chunks of 128.
// qw = q@Wq computed in-block. Epilogue: scores -> softmax -> user_interest,
// written straight into dnn_in. XOR-swizzled LDS (k ^= (row&7)*8).
__global__ __launch_bounds__(256, 3) void din_fused(
    const int* __restrict__ hist_ids, const int* __restrict__ feedid,
    const float* __restrict__ feed_table,
    const u16* __restrict__ WHP_T, const u16* __restrict__ WQ_T,
    const float* __restrict__ b1, const float* __restrict__ w2v,
    const float* __restrict__ b2p, u16* __restrict__ dnn_in)
{
    __shared__ u16 Wc[128 * 128];     // W'_b chunk [n][k] bf16 (swizzled)
    __shared__ u16 Hc[64 * 128];      // h chunk [m][k] bf16 (swizzled)
    __shared__ float qf[512];         // q_b (f32)
    __shared__ float tmp[256];        // qpart (prologue) / sred (epilogue)
    __shared__ float qwb[128];        // q@Wq + b1
    __shared__ float w2s[128];
    __shared__ int   hids[64];
    __shared__ float scf[64];         // scores -> attn (in place)

    int b = blockIdx.x;
    int t = threadIdx.x, w = t >> 6, lane = t & 63;
    int fid = feedid[b];

    // ---- prologue ----
    {
        float2 qv = *(const float2*)&feed_table[(size_t)fid * FDIM + t * 2];
        qf[t * 2] = qv.x; qf[t * 2 + 1] = qv.y;
    }
    if (t < 64) hids[t] = (t < LL) ? hist_ids[b * LL + t] : 0;
    if (t < 128) w2s[t] = w2v[t];
    __syncthreads();

    // qwb[col] = q . Wq[:,col] + b1[col]  (2 threads per col)
    {
        int col = t >> 1, seg = t & 1;
        const u16* wq = WQ_T + (size_t)col * 512 + seg * 256;
        const float* qp = &qf[seg * 256];
        float s = 0.f;
        #pragma unroll
        for (int g2 = 0; g2 < 32; ++g2) {
            ushort8 w8 = *(const ushort8*)(wq + g2 * 8);
            float4 q0 = *(const float4*)(qp + g2 * 8);
            float4 q1 = *(const float4*)(qp + g2 * 8 + 4);
            s += q0.x*bf2f(w8[0]) + q0.y*bf2f(w8[1]) + q0.z*bf2f(w8[2]) + q0.w*bf2f(w8[3])
               + q1.x*bf2f(w8[4]) + q1.y*bf2f(w8[5]) + q1.z*bf2f(w8[6]) + q1.w*bf2f(w8[7]);
        }
        tmp[t] = s;
    }
    __syncthreads();
    if (t < 128) qwb[t] = tmp[t * 2] + tmp[t * 2 + 1] + b1[t];

    f32x4 acc[4][2];
    f32x4 zz = {0.f, 0.f, 0.f, 0.f};
    #pragma unroll
    for (int i = 0; i < 4; ++i)
        #pragma unroll
        for (int j = 0; j < 2; ++j) acc[i][j] = zz;

    for (int kt = 0; kt < 4; ++kt) {
        // stage W' chunk: Wc[n][k] = bf16(Wh_T[n][K0+k] + q[K0+k]*Wp_T[n][K0+k])
        {
            int n = t >> 1, kh = (t & 1) * 64;
            const u16* whp = WHP_T + (size_t)n * 1024 + kt * 128 + kh;
            const float* qp = &qf[kt * 128 + kh];
            #pragma unroll
            for (int g2 = 0; g2 < 8; ++g2) {
                ushort8 wh = *(const ushort8*)(whp + g2 * 8);
                ushort8 wp = *(const ushort8*)(whp + 512 + g2 * 8);
                float4 q0 = *(const float4*)(qp + g2 * 8);
                float4 q1 = *(const float4*)(qp + g2 * 8 + 4);
                ushort8 wc;
                wc[0] = f2bf(bf2f(wh[0]) + q0.x * bf2f(wp[0]));
                wc[1] = f2bf(bf2f(wh[1]) + q0.y * bf2f(wp[1]));
                wc[2] = f2bf(bf2f(wh[2]) + q0.z * bf2f(wp[2]));
                wc[3] = f2bf(bf2f(wh[3]) + q0.w * bf2f(wp[3]));
                wc[4] = f2bf(bf2f(wh[4]) + q1.x * bf2f(wp[4]));
                wc[5] = f2bf(bf2f(wh[5]) + q1.y * bf2f(wp[5]));
                wc[6] = f2bf(bf2f(wh[6]) + q1.z * bf2f(wp[6]));
                wc[7] = f2bf(bf2f(wh[7]) + q1.w * bf2f(wp[7]));
                int k = kh + g2 * 8;
                *(ushort8*)&Wc[n * 128 + (k ^ ((n & 7) * 8))] = wc;
            }
        }
        // stage h chunk: Hc[r][k] (rows >= LL zero-filled once)
        {
            int r = t >> 2, ks = (t & 3) * 32;
            if (r < LL) {
                const float* hp = feed_table + (size_t)hids[r] * FDIM + kt * 128 + ks;
                #pragma unroll
                for (int g2 = 0; g2 < 4; ++g2) {
                    float4 h0 = *(const float4*)(hp + g2 * 8);
                    float4 h1 = *(const float4*)(hp + g2 * 8 + 4);
                    ushort8 hv; cvt8(h0, h1, hv);
                    int k = ks + g2 * 8;
                    *(ushort8*)&Hc[r * 128 + (k ^ ((r & 7) * 8))] = hv;
                }
            } else if (kt == 0) {
                ushort8 zv = {0,0,0,0,0,0,0,0};
                #pragma unroll
                for (int g2 = 0; g2 < 4; ++g2) {
                    int k = ks + g2 * 8;
                    *(ushort8*)&Hc[r * 128 + (k ^ ((r & 7) * 8))] = zv;
                }
            }
        }
        __syncthreads();
        // MFMA: wave w owns cols w*32..w*32+31; all 64 rows; K=128
        #pragma unroll
        for (int ks_ = 0; ks_ < 4; ++ks_) {
            int kk = ks_ * 32 + (lane >> 4) * 8;
            short8 a[4], bb[2];
            #pragma unroll
            for (int i = 0; i < 4; ++i) {
                int row = i * 16 + (lane & 15);
                a[i] = *(const short8*)&Hc[row * 128 + (kk ^ ((row & 7) * 8))];
            }
            #pragma unroll
            for (int j = 0; j < 2; ++j) {
                int n = w * 32 + j * 16 + (lane & 15);
                bb[j] = *(const short8*)&Wc[n * 128 + (kk ^ ((n & 7) * 8))];
            }
            __builtin_amdgcn_s_setprio(1);
            #pragma unroll
            for (int i = 0; i < 4; ++i)
                #pragma unroll
                for (int j = 0; j < 2; ++j)
                    acc[i][j] = __builtin_amdgcn_mfma_f32_16x16x32_bf16(
                        a[i], bb[j], acc[i][j], 0, 0, 0);
            __builtin_amdgcn_s_setprio(0);
        }
        __syncthreads();
    }

    // ---- epilogue 1: scores[row] = sum_col relu(acc + qwb) * w2 ----
    float b2 = b2p[0];
    #pragma unroll
    for (int i = 0; i < 4; ++i) {
        #pragma unroll
        for (int r = 0; r < 4; ++r) {
            int row = i * 16 + (lane >> 4) * 4 + r;
            float s = 0.f;
            #pragma unroll
            for (int j = 0; j < 2; ++j) {
                int col = w * 32 + j * 16 + (lane & 15);
                float v = acc[i][j][r] + qwb[col];
                s += fmaxf(v, 0.f) * w2s[col];
            }
            s += __shfl_xor(s, 1, 64);
            s += __shfl_xor(s, 2, 64);
            s += __shfl_xor(s, 4, 64);
            s += __shfl_xor(s, 8, 64);
            if ((lane & 15) == 0) tmp[row * 4 + w] = s;
        }
    }
    __syncthreads();
    if (t < 64)
        scf[t] = tmp[t * 4] + tmp[t * 4 + 1] + tmp[t * 4 + 2] + tmp[t * 4 + 3] + b2;
    __syncthreads();
    // ---- epilogue 2: softmax over 50 ----
    if (w == 0) {
        float x = (lane < LL) ? scf[lane] : -1e30f;
        float mx = wave_max(x);
        float e = (lane < LL) ? __expf(x - mx) : 0.f;
        float ssum = wave_sum(e);
        scf[lane] = e / ssum;
    }
    __syncthreads();
    // ---- epilogue 3: user_interest[d] = sum_l attn[l] * h[l][d] (h L2-hot) ----
    int d = t * 2;
    float a0 = 0.f, a1 = 0.f;
    #pragma unroll 5
    for (int l = 0; l < LL; ++l) {
        float2 hv = *(const float2*)&feed_table[(size_t)hids[l] * FDIM + d];
        float al = scf[l];
        a0 += al * hv.x;
        a1 += al * hv.y;
    }
    dnn_in[(size_t)b * KDNN + 648 + d] = f2bf(a0);
    dnn_in[(size_t)b * KDNN + 648 + d + 1] = f2bf(a1);
}

// ---------- K5: MMOE + task heads ----------
__global__ __launch_bounds__(256) void mmoe_head(
    const float* __restrict__ dnn_out, const float* __restrict__ expert_w,
    const float* __restrict__ gate_w, const float* __restrict__ out_w,
    const float* __restrict__ out_b, float* __restrict__ out)
{
    int wave = threadIdx.x >> 6, lane = threadIdx.x & 63;
    int b = blockIdx.x * 4 + wave;
    __shared__ float ds[4][128];
    __shared__ float eo[4][64];
    __shared__ float gt[4][32];
    ds[wave][lane] = dnn_out[b * 128 + lane];
    ds[wave][lane + 64] = dnn_out[b * 128 + 64 + lane];
    __syncthreads();
    int e = lane >> 3, o = lane & 7;
    float acc = 0.f;
    for (int k = 0; k < 128; ++k)
        acc += ds[wave][k] * expert_w[(e * 128 + k) * 8 + o];
    eo[wave][lane] = acc;
    if (lane < 32) {
        int tt = lane >> 3, ee = lane & 7;
        float g = 0.f;
        for (int k = 0; k < 128; ++k)
            g += ds[wave][k] * gate_w[(tt * 128 + k) * 8 + ee];
        float m = g;
        #pragma unroll
        for (int off = 4; off; off >>= 1) m = fmaxf(m, __shfl_xor(m, off, 8));
        float ex = __expf(g - m);
        float s = ex;
        #pragma unroll
        for (int off = 4; off; off >>= 1) s += __shfl_xor(s, off, 8);
        gt[wave][lane] = ex / s;
    }
    __syncthreads();
    if (lane < 32) {
        int tt = lane >> 3, o2 = lane & 7;
        float to = 0.f;
        #pragma unroll
        for (int ee = 0; ee < 8; ++ee)
            to += gt[wave][tt * 8 + ee] * eo[wave][ee * 8 + o2];
        float pl = to * out_w[tt * 8 + o2];
        #pragma unroll
        for (int off = 4; off; off >>= 1) pl += __shfl_xor(pl, off, 8);
        if (o2 == 0) {
            float logit = pl + out_b[tt];
            out[b * 4 + tt] = 1.f / (1.f + __expf(-logit));
        }
    }
}

// ---------- host ----------
extern "C" void kernel_launch(void* const* d_in, const int* in_sizes, int n_in,
                              void* d_out, int out_size, void* d_ws, size_t ws_size,
                              hipStream_t stream)
{
    const int*   sparse_ids = (const int*)d_in[0];
    const float* dense      = (const float*)d_in[1];
    const int*   feedid     = (const int*)d_in[2];
    const int*   hist_ids   = (const int*)d_in[3];
    const float* emb_tables = (const float*)d_in[4];
    const float* feed_table = (const float*)d_in[5];
    const float* attn_w1    = (const float*)d_in[6];
    const float* attn_b1    = (const float*)d_in[7];
    const float* attn_w2    = (const float*)d_in[8];
    const float* attn_b2    = (const float*)d_in[9];
    const float* dnn_w1     = (const float*)d_in[10];
    const float* dnn_b1     = (const float*)d_in[11];
    const float* dnn_w2     = (const float*)d_in[12];
    const float* dnn_b2     = (const float*)d_in[13];
    const float* expert_w   = (const float*)d_in[14];
    const float* gate_w     = (const float*)d_in[15];
    const float* out_w      = (const float*)d_in[16];
    const float* out_b      = (const float*)d_in[17];
    float* out = (float*)d_out;

    char* ws = (char*)d_ws;
    size_t off = 0;
    auto alloc = [&](size_t bytes) {
        char* p = ws + off;
        off += (bytes + 255) & ~(size_t)255;
        return p;
    };
    u16* WHP_T = (u16*)alloc(131072 * 2);
    u16* WQ_T  = (u16*)alloc(65536 * 2);
    u16* W1D_T = (u16*)alloc((size_t)HID1 * KDNN * 2);
    u16* W2D_T = (u16*)alloc((size_t)HID2 * HID1 * 2);
    u16* DNNIN = (u16*)alloc((size_t)BB * KDNN * 2);
    u16* Z     = (u16*)alloc((size_t)BB * HID1 * 2);
    float* DOUT= (float*)alloc((size_t)BB * HID2 * 4);

    prep_weights<<<2112, 256, 0, stream>>>(attn_w1, dnn_w1, dnn_w2,
                                           WHP_T, WQ_T, W1D_T, W2D_T);
    gather_b<<<BB, 256, 0, stream>>>(sparse_ids, dense, feedid, emb_tables,
                                     feed_table, DNNIN);
    din_fused<<<BB, 256, 0, stream>>>(hist_ids, feedid, feed_table,
                                      WHP_T, WQ_T, attn_b1, attn_w2, attn_b2,
                                      DNNIN);
    gemm_bt<64, true, true><<<dim3(BB / 64, HID1 / 128), 256, 0, stream>>>(
        DNNIN, KDNN, W1D_T, KDNN, dnn_b1, Z, BB, HID1, KDNN);
    gemm_bt<64, true, false><<<dim3(BB / 64, 1), 256, 0, stream>>>(
        Z, HID1, W2D_T, HID1, dnn_b2, DOUT, BB, HID2, HID1);
    mmoe_head<<<BB / 4, 256, 0, stream>>>(DOUT, expert_w, gate_w, out_w,
                                          out_b, out);
}